// Round 14
// baseline (3781.813 us; speedup 1.0000x reference)
//
#include <hip/hip_runtime.h>
#include <hip/hip_bf16.h>

typedef __hip_bfloat16 bf16;
typedef __attribute__((ext_vector_type(8))) short short8;
typedef __attribute__((ext_vector_type(4))) float float4v;

#define BATCH 8
#define SEQ   1568            // 14*14*8 tokens per batch
#define M_TOK (BATCH*SEQ)     // 12544
#define DM    768
#define DI    1536
#define XZW   3072            // fused in_proj output row width (x | z)
#define DS    16
#define DTR   48
#define NCLS  1000
#define LAYERS 4
#define CHUNK 112             // scan chunk length (7 tiles of 16)
#define NCH   14              // SEQ / CHUNK
#define DBCW  128             // padded dbc row width

__device__ __forceinline__ float b2f(bf16 v){ return __bfloat162float(v); }
__device__ __forceinline__ bf16  f2b(float v){ return __float2bfloat16(v); }
__device__ __forceinline__ float us2f(unsigned short u){
    unsigned v = ((unsigned)u) << 16; float f; __builtin_memcpy(&f, &v, 4); return f;
}
__device__ __forceinline__ short f2bs(float v){
    bf16 r = f2b(v); unsigned short u; __builtin_memcpy(&u, &r, 2); return (short)u;
}
// async global->LDS, 16B per lane; LDS dest = uniform base + lane*16
__device__ __forceinline__ void gload_lds16(const void* g, void* l){
    __builtin_amdgcn_global_load_lds(
        (const __attribute__((address_space(1))) void*)g,
        (__attribute__((address_space(3))) void*)l, 16, 0, 0);
}
// VALU-pipe cross-lane add via DPP. CTRL immediate (template).
template<int CTRL>
__device__ __forceinline__ float dpp_add(float p){
    int pi; __builtin_memcpy(&pi, &p, 4);
    int mi = __builtin_amdgcn_update_dpp(pi, pi, CTRL, 0xF, 0xF, false);
    float m; __builtin_memcpy(&m, &mi, 4);
    return p + m;
}

// ---------------------------------------------------------------- dtype probe
__global__ void detect_dtype(const unsigned short* __restrict__ probe, unsigned* __restrict__ flag)
{
    if (threadIdx.x == 0 && blockIdx.x == 0) flag[0] = (probe[0] == 0) ? 1u : 0u;  // 1 = fp32
}

// ---------------------------------------------------------------- batched input conversion
struct CvtArgs {
    const void* src[21];
    void*       dst[21];
    int         n[21];       // element count
    int         n8[21];      // ceil(n/8)
    unsigned    f32mask;     // bit k: PERMUTED slot k converts to fp32
    int         total8;      // sum of n8
};

__global__ __launch_bounds__(256)
void convert_all8(CvtArgs a, const unsigned* __restrict__ flag)
{
    int g8 = blockIdx.x*256 + threadIdx.x;
    if (g8 >= a.total8) return;
    int i = 0, base = 0;
    while (g8 >= base + a.n8[i]) { base += a.n8[i]; ++i; }
    int j = (g8 - base)*8;
    bool in_f32  = flag[0] != 0;
    bool out_f32 = (a.f32mask >> i) & 1u;
    if (j + 8 <= a.n[i]) {
        if (in_f32) {
            float4v v0 = *(const float4v*)((const float*)a.src[i] + j);
            float4v v1 = *(const float4v*)((const float*)a.src[i] + j + 4);
            if (out_f32) {
                *(float4v*)((float*)a.dst[i] + j)     = v0;
                *(float4v*)((float*)a.dst[i] + j + 4) = v1;
            } else {
                short8 o;
                #pragma unroll
                for (int k = 0; k < 4; ++k) { o[k] = f2bs(v0[k]); o[k+4] = f2bs(v1[k]); }
                *(short8*)((short*)a.dst[i] + j) = o;
            }
        } else {
            short8 v = *(const short8*)((const short*)a.src[i] + j);
            if (out_f32) {
                float4v v0, v1;
                #pragma unroll
                for (int k = 0; k < 4; ++k) {
                    v0[k] = us2f((unsigned short)v[k]);
                    v1[k] = us2f((unsigned short)v[k+4]);
                }
                *(float4v*)((float*)a.dst[i] + j)     = v0;
                *(float4v*)((float*)a.dst[i] + j + 4) = v1;
            } else {
                *(short8*)((short*)a.dst[i] + j) = v;
            }
        }
    } else {
        for (int q = j; q < a.n[i]; ++q) {
            float v = in_f32 ? ((const float*)a.src[i])[q] : b2f(((const bf16*)a.src[i])[q]);
            if (out_f32) ((float*)a.dst[i])[q] = v;
            else         ((bf16*) a.dst[i])[q] = f2b(v);
        }
    }
}

// ---------------------------------------------------------------- weight pad (run once)
// dtw (L,DI,48) -> (L,DI,64) zero-padded cols
__global__ __launch_bounds__(256)
void pad_dtw(const bf16* __restrict__ src, bf16* __restrict__ dst)
{
    int idx = blockIdx.x*256 + threadIdx.x;          // < L*DI*64
    if (idx >= LAYERS*DI*64) return;
    int l = idx / (DI*64);
    int d = (idx / 64) % DI;
    int c = idx % 64;
    dst[idx] = (c < DTR) ? src[((size_t)l*DI + d)*DTR + c] : f2b(0.f);
}

// ---------------------------------------------------------------- gather patches (per batch-group)
__global__ __launch_bounds__(256)
void gather_patches(const bf16* __restrict__ x, bf16* __restrict__ Ap, int b0)
{
    size_t idx = (size_t)blockIdx.x*256 + threadIdx.x;
    int i = (int)(idx & 255);
    int m = (int)(idx >> 8);
    int b = b0 + m / SEQ, s = m % SEQ;
    int hw = s >> 3, c = s & 7;
    int h = hw / 14, w = hw % 14;
    int p = i >> 4, q = i & 15;
    Ap[idx] = x[(((size_t)(b*8 + c)*224) + h*16 + p)*224 + w*16 + q];
}

// ---------------------------------------------------------------- MFMA GEMM, ragged-safe (128x128, BK=32)
// Small grids (<192 blocks): VGPR-staged loads software-pipeline under MFMA.
// Split-K: gridDim.z slices; epi 5 stores fp32 partials per slice.
__global__ __launch_bounds__(256)
void gemm_mfma(const bf16* __restrict__ A, int lda,
               const bf16* __restrict__ W, int ldw,
               float* __restrict__ Cf, bf16* __restrict__ Cb, int ldc,
               const float* __restrict__ bias, const float* __restrict__ chan,
               int M, int N, int K, int epi)
{
    __shared__ short As[128*40];   // 32 + 8 pad elems per row (80B stride, 16B aligned)
    __shared__ short Bs[128*40];
    int kb = blockIdx.z * K;       // K-slice base (0 when gridDim.z==1)
    A += kb;  W += kb;
    int tid  = threadIdx.x;
    int m0   = blockIdx.x*128, n0 = blockIdx.y*128;
    int lane = tid & 63, wv = tid >> 6;
    int wm = (wv >> 1)*64, wn = (wv & 1)*64;
    int l15 = lane & 15, quad = lane >> 4;

    float4v acc[4][4];
    #pragma unroll
    for (int i = 0; i < 4; ++i)
        #pragma unroll
        for (int j = 0; j < 4; ++j) acc[i][j] = (float4v){0.f,0.f,0.f,0.f};

    const short8 zv8 = {0,0,0,0,0,0,0,0};
    for (int k0 = 0; k0 < K; k0 += 32) {
        #pragma unroll
        for (int u = 0; u < 2; ++u) {
            int c   = tid*2 + u;           // 512 chunks of 16B
            int row = c >> 2, ch = c & 3;
            bool kok = (k0 + ch*8 + 8) <= K;   // K is a multiple of 8
            short8 va = (kok && m0 + row < M)
                ? *(const short8*)((const short*)A + (size_t)(m0+row)*lda + k0 + ch*8) : zv8;
            *(short8*)(As + row*40 + ch*8) = va;
            short8 vb = (kok && n0 + row < N)
                ? *(const short8*)((const short*)W + (size_t)(n0+row)*ldw + k0 + ch*8) : zv8;
            *(short8*)(Bs + row*40 + ch*8) = vb;
        }
        __syncthreads();
        short8 av[4], bv[4];
        #pragma unroll
        for (int i = 0; i < 4; ++i) av[i] = *(const short8*)(As + (wm + i*16 + l15)*40 + quad*8);
        #pragma unroll
        for (int j = 0; j < 4; ++j) bv[j] = *(const short8*)(Bs + (wn + j*16 + l15)*40 + quad*8);
        #pragma unroll
        for (int i = 0; i < 4; ++i)
            #pragma unroll
            for (int j = 0; j < 4; ++j)
                acc[i][j] = __builtin_amdgcn_mfma_f32_16x16x32_bf16(av[i], bv[j], acc[i][j], 0, 0, 0);
        __syncthreads();
    }

    // C/D layout: col = lane&15, row = quad*4 + reg
    #pragma unroll
    for (int i = 0; i < 4; ++i) {
        #pragma unroll
        for (int j = 0; j < 4; ++j) {
            int gn = n0 + wn + j*16 + l15;
            if (gn >= N) continue;
            #pragma unroll
            for (int r = 0; r < 4; ++r) {
                int gm = m0 + wm + i*16 + quad*4 + r;
                if (gm >= M) continue;
                float v = acc[i][j][r];
                size_t off = (size_t)gm*ldc + gn;
                if (epi == 0)      Cb[off] = f2b(v);
                else if (epi == 1) {
                    v += bias[gn];
                    v = (v > 20.f) ? v : log1pf(__expf(v));
                    Cb[off] = f2b(v);
                }
                else if (epi == 2) Cf[off] += v;
                else if (epi == 5) Cf[(size_t)blockIdx.z*((size_t)M*ldc) + off] = v;
                else               Cf[off] = v + bias[gn] + chan[(size_t)(gm & 7)*N + gn];
            }
        }
    }
}

// ---------------------------------------------------------------- split-K combine for x_proj
__global__ __launch_bounds__(256)
void dbc_combine(const float* __restrict__ dbcf, bf16* __restrict__ dbc, int MG)
{
    int idx = blockIdx.x*256 + threadIdx.x;   // < MG*20
    if (idx >= MG*20) return;
    int m = idx / 20, c4 = (idx % 20)*4;
    float4v a = *(const float4v*)(dbcf + (size_t)m*80 + c4);
    float4v b = *(const float4v*)(dbcf + (size_t)MG*80 + (size_t)m*80 + c4);
    ushort4 o;
    o.x = (unsigned short)f2bs(a[0] + b[0]);
    o.y = (unsigned short)f2bs(a[1] + b[1]);
    o.z = (unsigned short)f2bs(a[2] + b[2]);
    o.w = (unsigned short)f2bs(a[3] + b[3]);
    *(ushort4*)((unsigned short*)dbc + (size_t)m*DBCW + c4) = o;
}

// ---------------------------------------------------------------- MFMA GEMM fast path (BK=32, linear LDS)
// Requires M%128==0, N%128==0, K%32==0, >=192 blocks (TLP hides barrier drain).
__global__ __launch_bounds__(256)
void gemm_mfma_fast(const bf16* __restrict__ A, int lda,
                    const bf16* __restrict__ W, int ldw,
                    float* __restrict__ Cf, bf16* __restrict__ Cb, int ldc,
                    const float* __restrict__ bias, const float* __restrict__ chan,
                    int N, int K, int epi)
{
    __shared__ short As[128*32];
    __shared__ short Bs[128*32];
    int tid  = threadIdx.x;
    int m0   = blockIdx.x*128, n0 = blockIdx.y*128;
    int lane = tid & 63, wv = tid >> 6;
    int wm = (wv >> 1)*64, wn = (wv & 1)*64;
    int l15 = lane & 15, quad = lane >> 4;

    int srow = (lane >> 2);          // row within 16-row chunk
    int skof = (lane & 3) * 8;       // k element offset within row

    float4v acc[4][4];
    #pragma unroll
    for (int i = 0; i < 4; ++i)
        #pragma unroll
        for (int j = 0; j < 4; ++j) acc[i][j] = (float4v){0.f,0.f,0.f,0.f};

    const short* Ab = (const short*)A;
    const short* Wb = (const short*)W;

    for (int k0 = 0; k0 < K; k0 += 32) {
        #pragma unroll
        for (int u = 0; u < 2; ++u) {
            int c = wv*2 + u;                 // chunk 0..7
            int row = c*16 + srow;
            gload_lds16(Ab + (size_t)(m0+row)*lda + k0 + skof, As + c*512);
            gload_lds16(Wb + (size_t)(n0+row)*ldw + k0 + skof, Bs + c*512);
        }
        __syncthreads();                       // drains vmcnt (compiler-inserted)
        short8 av[4], bv[4];
        #pragma unroll
        for (int i = 0; i < 4; ++i) av[i] = *(const short8*)(As + (wm + i*16 + l15)*32 + quad*8);
        #pragma unroll
        for (int j = 0; j < 4; ++j) bv[j] = *(const short8*)(Bs + (wn + j*16 + l15)*32 + quad*8);
        #pragma unroll
        for (int i = 0; i < 4; ++i)
            #pragma unroll
            for (int j = 0; j < 4; ++j)
                acc[i][j] = __builtin_amdgcn_mfma_f32_16x16x32_bf16(av[i], bv[j], acc[i][j], 0, 0, 0);
        __syncthreads();
    }

    #pragma unroll
    for (int i = 0; i < 4; ++i) {
        #pragma unroll
        for (int j = 0; j < 4; ++j) {
            int gn = n0 + wn + j*16 + l15;
            #pragma unroll
            for (int r = 0; r < 4; ++r) {
                int gm = m0 + wm + i*16 + quad*4 + r;
                float v = acc[i][j][r];
                size_t off = (size_t)gm*ldc + gn;
                if (epi == 0)      Cb[off] = f2b(v);
                else if (epi == 1) {
                    v += bias[gn];
                    v = (v > 20.f) ? v : log1pf(__expf(v));
                    Cb[off] = f2b(v);
                }
                else if (epi == 2) Cf[off] += v;
                else               Cf[off] = v + bias[gn] + chan[(size_t)(gm & 7)*N + gn];
            }
        }
    }
}

// ---------------------------------------------------------------- LayerNorm 768 (fp32 in, bf16 out)
__global__ __launch_bounds__(256)
void ln768(const float* __restrict__ X, const float* __restrict__ w,
           const float* __restrict__ bb, bf16* __restrict__ out)
{
    __shared__ float red[8];
    size_t t = blockIdx.x;
    const float* x = X + t*DM;
    float v[3]; float s = 0.f, s2 = 0.f;
    #pragma unroll
    for (int r = 0; r < 3; ++r) {
        v[r] = x[threadIdx.x + 256*r];
        s += v[r]; s2 += v[r]*v[r];
    }
    #pragma unroll
    for (int o = 32; o; o >>= 1) { s += __shfl_down(s, o, 64); s2 += __shfl_down(s2, o, 64); }
    if ((threadIdx.x & 63) == 0) { red[threadIdx.x >> 6] = s; red[(threadIdx.x >> 6) + 4] = s2; }
    __syncthreads();
    s  = red[0]+red[1]+red[2]+red[3];
    s2 = red[4]+red[5]+red[6]+red[7];
    float mu  = s * (1.f/DM);
    float inv = rsqrtf(fmaxf(s2*(1.f/DM) - mu*mu, 0.f) + 1e-5f);
    #pragma unroll
    for (int r = 0; r < 3; ++r) {
        int i = threadIdx.x + 256*r;
        out[t*DM + i] = f2b((v[r]-mu)*inv*w[i] + bb[i]);
    }
}

// ---------------------------------------------------------------- causal depthwise conv (k=4) + silu
// reads x-half of fused xz (row stride XZW); writes dense DI-wide xc
__global__ __launch_bounds__(256)
void conv_silu(const bf16* __restrict__ xz, const float* __restrict__ cw,
               const float* __restrict__ cb, bf16* __restrict__ xc)
{
    size_t idx = (size_t)blockIdx.x*256 + threadIdx.x;   // < g*SEQ*DI/8
    int dv = (int)(idx % (DI/8));
    int m  = (int)(idx / (DI/8));
    int b = m / SEQ, t = m % SEQ;                        // local batch
    int d = dv*8;

    float4v cwq[8];
    #pragma unroll
    for (int j = 0; j < 8; ++j) cwq[j] = *(const float4v*)(cw + (size_t)(d+j)*4);

    float acc[8];
    #pragma unroll
    for (int j = 0; j < 8; ++j) acc[j] = cb[d+j];

    #pragma unroll
    for (int k = 0; k < 4; ++k) {
        int tt = t + k - 3;
        if (tt >= 0) {
            short8 v = *(const short8*)((const short*)xz + (size_t)(b*SEQ + tt)*XZW + d);
            #pragma unroll
            for (int j = 0; j < 8; ++j)
                acc[j] += us2f((unsigned short)v[j]) * cwq[j][k];
        }
    }
    short8 o;
    #pragma unroll
    for (int j = 0; j < 8; ++j) {
        float sig = 1.f/(1.f + __expf(-acc[j]));
        o[j] = f2bs(acc[j]*sig);
    }
    *(short8*)((short*)xc + idx*8) = o;
}

// ---------------------------------------------------------------- selective scan: chunked 2-pass,
// 4 states/lane (64 d x 4 state-quads per 256-thread block); DPP quad reduction.
// dbc rows DBCW-wide. pass2 writes y into the dead x-half of xz (row stride XZW).

__global__ __launch_bounds__(256)
void scan_pass1(const bf16* __restrict__ dt, const bf16* __restrict__ x,
                const bf16* __restrict__ dbc, const float* __restrict__ Alog,
                float* __restrict__ hend, float* __restrict__ Pprod, int nin2)
{
    __shared__ float dtT[2][64][20], xT[2][64][20];
    __shared__ float BsT[2][16][16];
    int c  = blockIdx.x / nin2;          // chunk 0..NCH-2
    int r  = blockIdx.x % nin2;
    int b  = r / 24;
    int d0 = (r % 24) * 64;
    int tid = threadIdx.x;
    int sq = tid & 3;        // state quad: states sq*4..sq*4+3
    int dl = tid >> 2;       // d-chain 0..63
    int d  = d0 + dl;

    float4v Aq = *(const float4v*)(Alog + (size_t)d*DS + sq*4);
    float A2[4], h[4];
    #pragma unroll
    for (int k = 0; k < 4; ++k) { A2[k] = -__expf(Aq[k]) * 1.44269504f; h[k] = 0.f; }
    float sdt = 0.f;

    int js = tid >> 4, dg = tid & 15;        // dt/x staging: step js, d-group dg*4
    bool doB = tid < 64;
    int j2 = tid >> 2;                       // B staging step (tid<64)

    const unsigned short* pdt = (const unsigned short*)dt + ((size_t)b*SEQ + js)*DI + d0 + dg*4;
    const unsigned short* px  = (const unsigned short*)x  + ((size_t)b*SEQ + js)*DI + d0 + dg*4;
    const unsigned short* pbc = (const unsigned short*)dbc + ((size_t)b*SEQ + (j2 & 15))*DBCW + DTR + sq*4;
    int tbase = c * CHUNK;
    const int NT = CHUNK/16;

    ushort4 vdt, vx, vbc;
    auto stage = [&](int buf){
        dtT[buf][dg*4+0][js] = us2f(vdt.x); dtT[buf][dg*4+1][js] = us2f(vdt.y);
        dtT[buf][dg*4+2][js] = us2f(vdt.z); dtT[buf][dg*4+3][js] = us2f(vdt.w);
        xT [buf][dg*4+0][js] = us2f(vx.x);  xT [buf][dg*4+1][js] = us2f(vx.y);
        xT [buf][dg*4+2][js] = us2f(vx.z);  xT [buf][dg*4+3][js] = us2f(vx.w);
        if (doB)
            *(float4v*)&BsT[buf][j2][sq*4] =
                (float4v){us2f(vbc.x), us2f(vbc.y), us2f(vbc.z), us2f(vbc.w)};
    };
    auto fetch = [&](int T){
        vdt = *(const ushort4*)(pdt + (size_t)(tbase + T*16)*DI);
        vx  = *(const ushort4*)(px  + (size_t)(tbase + T*16)*DI);
        if (doB) vbc = *(const ushort4*)(pbc + (size_t)(tbase + T*16)*DBCW);
    };

    fetch(0); stage(0); fetch(1);
    __syncthreads();

    for (int t = 0; t < NT; ++t) {
        int cur = t & 1;
        if (t+1 < NT) stage(cur^1);
        if (t+2 < NT) fetch(t+2);
        #pragma unroll
        for (int jj = 0; jj < 16; jj += 4) {
            float4v dtq = *(const float4v*)&dtT[cur][dl][jj];
            float4v xq  = *(const float4v*)&xT [cur][dl][jj];
            #pragma unroll
            for (int k2 = 0; k2 < 4; ++k2) {
                float dtv = dtq[k2];
                float dtx = dtv * xq[k2];
                float4v Bq = *(const float4v*)&BsT[cur][jj+k2][sq*4];
                #pragma unroll
                for (int k = 0; k < 4; ++k)
                    h[k] = exp2f(dtv*A2[k])*h[k] + dtx*Bq[k];
                sdt += dtv;
            }
        }
        __syncthreads();
    }
    size_t o = (((size_t)c*nin2 + r)*256 + tid)*4;
    *(float4v*)(hend + o) = (float4v){h[0], h[1], h[2], h[3]};
    *(float4v*)(Pprod + o) = (float4v){exp2f(A2[0]*sdt), exp2f(A2[1]*sdt),
                                       exp2f(A2[2]*sdt), exp2f(A2[3]*sdt)};
}

__global__ __launch_bounds__(256)
void scan_mid(const float* __restrict__ hend, const float* __restrict__ Pprod,
              float* __restrict__ hstart, int nin2)
{
    int r = blockIdx.x, tid = threadIdx.x;
    float4v h = (float4v){0.f,0.f,0.f,0.f};
    *(float4v*)(hstart + ((size_t)r*256 + tid)*4) = h;
    for (int c = 1; c < NCH; ++c) {
        size_t p = (((size_t)(c-1)*nin2 + r)*256 + tid)*4;
        float4v P  = *(const float4v*)(Pprod + p);
        float4v he = *(const float4v*)(hend + p);
        h = P*h + he;
        *(float4v*)(hstart + (((size_t)c*nin2 + r)*256 + tid)*4) = h;
    }
}

__global__ __launch_bounds__(256)
void scan_pass2(const bf16* __restrict__ dt, const bf16* __restrict__ x,
                const bf16* __restrict__ dbc, const float* __restrict__ Alog,
                const float* __restrict__ Dpar, const float* __restrict__ hstart,
                bf16* __restrict__ y, int nin2)   // y: row stride XZW (xz x-half)
{
    __shared__ float dtT[2][64][20], xT[2][64][20];
    __shared__ float BsT[2][16][16], CsT[2][16][16];
    __shared__ bf16  ys[16][64];
    int c  = blockIdx.x / nin2;
    int r  = blockIdx.x % nin2;
    int b  = r / 24;
    int d0 = (r % 24) * 64;
    int tid = threadIdx.x;
    int sq = tid & 3;
    int dl = tid >> 2;
    int d  = d0 + dl;

    float4v Aq = *(const float4v*)(Alog + (size_t)d*DS + sq*4);
    float A2[4], h[4];
    {
        float4v h0 = *(const float4v*)(hstart + (((size_t)c*nin2 + r)*256 + tid)*4);
        #pragma unroll
        for (int k = 0; k < 4; ++k) { A2[k] = -__expf(Aq[k]) * 1.44269504f; h[k] = h0[k]; }
    }
    float Dv = Dpar[d];

    int js = tid >> 4, dg = tid & 15;
    bool doBC = tid < 128;
    int j2 = (tid & 63) >> 2;

    const unsigned short* pdt = (const unsigned short*)dt + ((size_t)b*SEQ + js)*DI + d0 + dg*4;
    const unsigned short* px  = (const unsigned short*)x  + ((size_t)b*SEQ + js)*DI + d0 + dg*4;
    const unsigned short* pbc = (const unsigned short*)dbc + ((size_t)b*SEQ + j2)*DBCW + DTR
                                + ((tid >= 64) ? DS : 0) + sq*4;
    float* bc0 = (tid < 64) ? &BsT[0][j2][sq*4] : &CsT[0][j2][sq*4];
    int tbase = c * CHUNK;
    const int NT = CHUNK/16;

    ushort4 vdt, vx, vbc;
    auto stage = [&](int buf){
        dtT[buf][dg*4+0][js] = us2f(vdt.x); dtT[buf][dg*4+1][js] = us2f(vdt.y);
        dtT[buf][dg*4+2][js] = us2f(vdt.z); dtT[buf][dg*4+3][js] = us2f(vdt.w);
        xT [buf][dg*4+0][js] = us2f(vx.x);  xT [buf][dg*4+1][js] = us2f(vx.y);
        xT [buf][dg*4+2][js] = us2f(vx.z);  xT [buf][dg*4+3][js] = us2f(vx.w);
        if (doBC)
            *(float4v*)(bc0 + (size_t)buf*256) =
                (float4v){us2f(vbc.x), us2f(vbc.y), us2f(vbc.z), us2f(vbc.w)};
    };
    auto fetch = [&](int T){
        vdt = *(const ushort4*)(pdt + (size_t)(tbase + T*16)*DI);
        vx  = *(const ushort4*)(px  + (size_t)(tbase + T*16)*DI);
        if (doBC) vbc = *(const ushort4*)(pbc + (size_t)(tbase + T*16)*DBCW);
    };

    fetch(0); stage(0); fetch(1);
    __syncthreads();

    for (int t = 0; t < NT; ++t) {
        int cur = t & 1;
        if (t+1 < NT) stage(cur^1);
        if (t+2 < NT) fetch(t+2);

        #pragma unroll
        for (int jj = 0; jj < 16; jj += 4) {
            float4v dtq = *(const float4v*)&dtT[cur][dl][jj];
            float4v xq  = *(const float4v*)&xT [cur][dl][jj];
            #pragma unroll
            for (int k2 = 0; k2 < 4; ++k2) {
                float dtv = dtq[k2];
                float xv  = xq[k2];
                float dtx = dtv * xv;
                float4v Bq = *(const float4v*)&BsT[cur][jj+k2][sq*4];
                float4v Cq = *(const float4v*)&CsT[cur][jj+k2][sq*4];
                float p = 0.f;
                #pragma unroll
                for (int k = 0; k < 4; ++k) {
                    h[k] = exp2f(dtv*A2[k])*h[k] + dtx*Bq[k];
                    p += h[k]*Cq[k];
                }
                p = dpp_add<0xB1>(p);    // quad_perm xor1 (within one d's quad)
                p = dpp_add<0x4E>(p);    // quad_perm xor2
                if (sq == 0) ys[jj+k2][dl] = f2b(p + Dv*xv);
            }
        }
        __syncthreads();                 // ys ready + next buf staged
        {
            size_t rowm = (size_t)(b*SEQ + tbase + t*16 + js);
            ushort4 vy = *(const ushort4*)((const unsigned short*)&ys[js][0] + dg*4);
            *(ushort4*)((unsigned short*)y + rowm*XZW + d0 + dg*4) = vy;
        }
        __syncthreads();                 // ys consumed
    }
}

// ---------------------------------------------------------------- LN(1536)*silu(z) gate
// y and z are the two halves of fused xz (row stride XZW); out dense DI-wide.
__global__ __launch_bounds__(192)
void gate_ln(const bf16* __restrict__ xz,
             const float* __restrict__ w, const float* __restrict__ bb,
             bf16* __restrict__ out)
{
    __shared__ float red[6];
    size_t t = blockIdx.x;
    int tid = threadIdx.x;
    int i0 = tid*8;
    short8 y8 = *(const short8*)((const short*)xz + t*XZW + i0);
    short8 z8 = *(const short8*)((const short*)xz + t*XZW + DI + i0);
    float vy[8];
    float s = 0.f, s2 = 0.f;
    #pragma unroll
    for (int j = 0; j < 8; ++j) {
        vy[j] = us2f((unsigned short)y8[j]);
        s += vy[j]; s2 += vy[j]*vy[j];
    }
    #pragma unroll
    for (int o = 32; o; o >>= 1) { s += __shfl_down(s, o, 64); s2 += __shfl_down(s2, o, 64); }
    if ((tid & 63) == 0) { red[tid >> 6] = s; red[(tid >> 6) + 3] = s2; }
    __syncthreads();
    s  = red[0]+red[1]+red[2];
    s2 = red[3]+red[4]+red[5];
    float mu  = s * (1.f/DI);
    float inv = rsqrtf(fmaxf(s2*(1.f/DI) - mu*mu, 0.f) + 1e-5f);
    float4v w0 = *(const float4v*)(w + i0);
    float4v w1 = *(const float4v*)(w + i0 + 4);
    float4v b0 = *(const float4v*)(bb + i0);
    float4v b1 = *(const float4v*)(bb + i0 + 4);
    short8 o8;
    #pragma unroll
    for (int j = 0; j < 8; ++j) {
        float zv = us2f((unsigned short)z8[j]);
        float sig = 1.f/(1.f + __expf(-zv));
        float wj = (j < 4) ? w0[j] : w1[j-4];
        float bj = (j < 4) ? b0[j] : b1[j-4];
        o8[j] = f2bs(((vy[j]-mu)*inv*wj + bj) * (zv*sig));
    }
    *(short8*)((short*)out + t*DI + i0) = o8;
}

// ---------------------------------------------------------------- mean pool, 2-stage
__global__ __launch_bounds__(256)
void pool_partial(const bf16* __restrict__ hf, float* __restrict__ part)
{
    int blk = blockIdx.x;            // BATCH*14
    int b = blk / NCH, c = blk % NCH;
    int tid = threadIdx.x;
    const bf16* p = hf + ((size_t)b*SEQ + c*CHUNK)*DM;
    float s0 = 0.f, s1 = 0.f, s2 = 0.f;
    for (int t = 0; t < CHUNK; ++t) {
        s0 += b2f(p[(size_t)t*DM + tid]);
        s1 += b2f(p[(size_t)t*DM + tid + 256]);
        s2 += b2f(p[(size_t)t*DM + tid + 512]);
    }
    part[(size_t)blk*DM + tid]       = s0;
    part[(size_t)blk*DM + tid + 256] = s1;
    part[(size_t)blk*DM + tid + 512] = s2;
}

__global__ __launch_bounds__(256)
void pool_finish(const float* __restrict__ part, float* __restrict__ pooled)
{
    int idx = blockIdx.x*256 + threadIdx.x;   // < BATCH*DM
    int b = idx / DM, dm = idx % DM;
    float s = 0.f;
    for (int c = 0; c < NCH; ++c) s += part[((size_t)b*NCH + c)*DM + dm];
    pooled[idx] = s * (1.f/SEQ);
}

// ---------------------------------------------------------------- classifier head
__global__ __launch_bounds__(256)
void head_kernel(const unsigned* __restrict__ flag,
                 const float* __restrict__ pooled, const bf16* __restrict__ hw,
                 const float* __restrict__ hb, void* __restrict__ out)
{
    int idx = blockIdx.x*256 + threadIdx.x;
    if (idx >= BATCH*NCLS) return;
    int b = idx & 7, n = idx >> 3;
    const float* p = pooled + b*DM;
    const unsigned short* w = (const unsigned short*)hw + (size_t)n*DM;
    float acc = hb[n];
    for (int k = 0; k < DM; k += 4) {
        ushort4 wv = *(const ushort4*)(w + k);
        acc += p[k]*us2f(wv.x) + p[k+1]*us2f(wv.y) + p[k+2]*us2f(wv.z) + p[k+3]*us2f(wv.w);
    }
    int o = b*NCLS + n;
    if (flag[0]) ((float*)out)[o] = acc;
    else         ((bf16*)out)[o]  = f2b(acc);
}

// ================================================================ launcher
extern "C" void kernel_launch(void* const* d_in, const int* in_sizes, int n_in,
                              void* d_out, int out_size, void* d_ws, size_t ws_size,
                              hipStream_t stream)
{
    (void)n_in; (void)out_size;
    dim3 blk(256);

    const bool is_f32[21] = { false, false, true, true, true, true, false, true, true,
                              false, false, true,  true, true, true, true, false,
                              true,  true,  false, true };

    size_t off = 0;
    auto carve = [&](size_t bytes) -> void* {
        void* q = (char*)d_ws + off;
        off += (bytes + 255) & ~(size_t)255;
        return q;
    };

    unsigned* flag = (unsigned*)carve(256);
    void* canon[21];
    for (int i = 0; i < 21; ++i)
        canon[i] = carve((size_t)in_sizes[i] * (is_f32[i] ? 4 : 2));

    float* residual = (float*)carve((size_t)M_TOK*DM*4);
    bf16*  hn       = (bf16*) carve((size_t)M_TOK*DM*2);
    float* pooled   = (float*)carve((size_t)BATCH*DM*4);
    float* poolpart = (float*)carve((size_t)BATCH*NCH*DM*4);
    bf16*  dtw_pad  = (bf16*) carve((size_t)LAYERS*DI*64*2);

    const size_t scanbuf1 = (size_t)NCH*96*256*4;   // per g-unit, per array
    const size_t inner1 = (((size_t)SEQ*XZW*2 + 255) & ~(size_t)255)      // xz
                          + 2*(((size_t)SEQ*DI*2 + 255) & ~(size_t)255)   // xc, dtb
                          + (((size_t)SEQ*DBCW*2 + 255) & ~(size_t)255)   // dbc
                          + 2*(((size_t)SEQ*80*4 + 255) & ~(size_t)255)   // dbcf (2 K-slices)
                          + 3*((scanbuf1 + 255) & ~(size_t)255);
    int g = 8;
    while (g > 1 && off + (size_t)g*inner1 > ws_size) g >>= 1;

    bf16* xz  = (bf16*)carve((size_t)g*SEQ*XZW*2);  // fused in_proj out; x-half doubles as Ap / ybuf
    bf16* xc  = (bf16*)carve((size_t)g*SEQ*DI*2);
    bf16* dtb = (bf16*)carve((size_t)g*SEQ*DI*2);   // also gated
    bf16* dbc = (bf16*)carve((size_t)g*SEQ*DBCW*2);
    float* dbcf = (float*)carve((size_t)g*SEQ*80*4*2);   // split-K partials
    float* hend   = (float*)carve((size_t)g*scanbuf1);
    float* Pprod  = (float*)carve((size_t)g*scanbuf1);
    float* hstart = (float*)carve((size_t)g*scanbuf1);
    bf16* Ap    = xz;          // patch staging (pre-layer, whole buffer free)
    bf16* gated = dtb;

    detect_dtype<<<1, 64, 0, stream>>>((const unsigned short*)d_in[4], flag);

    // ---- single batched conversion, 8 elems/thread; size-desc order ----
    {
        int order[21];
        for (int i = 0; i < 21; ++i) order[i] = i;
        for (int a = 0; a < 21; ++a)
            for (int b2 = a+1; b2 < 21; ++b2)
                if (in_sizes[order[b2]] > in_sizes[order[a]]) {
                    int tmp = order[a]; order[a] = order[b2]; order[b2] = tmp;
                }
        CvtArgs ca;
        ca.f32mask = 0; ca.total8 = 0;
        for (int k = 0; k < 21; ++k) {
            int i = order[k];
            ca.src[k] = d_in[i];
            ca.dst[k] = canon[i];
            ca.n[k]   = in_sizes[i];
            ca.n8[k]  = (in_sizes[i] + 7)/8;
            ca.total8 += ca.n8[k];
            if (is_f32[i]) ca.f32mask |= (1u << k);
        }
        convert_all8<<<(ca.total8 + 255)/256, blk, 0, stream>>>(ca, flag);
    }

    const bf16*  xin   = (const bf16*) canon[0];
    const bf16*  pw    = (const bf16*) canon[1];
    const float* pb    = (const float*)canon[2];
    const float* chan  = (const float*)canon[3];
    const float* nw    = (const float*)canon[4];
    const float* nb    = (const float*)canon[5];
    const bf16*  ipw   = (const bf16*) canon[6];
    const float* cw    = (const float*)canon[7];
    const float* cb    = (const float*)canon[8];
    const bf16*  xpw   = (const bf16*) canon[9];
    const bf16*  dtw   = (const bf16*) canon[10];
    const float* dtbia = (const float*)canon[11];
    const float* Alog  = (const float*)canon[12];
    const float* Dpar  = (const float*)canon[13];
    const float* snw   = (const float*)canon[14];
    const float* snb   = (const float*)canon[15];
    const bf16*  opw   = (const bf16*) canon[16];
    const float* nfw   = (const float*)canon[17];
    const float* nfb   = (const float*)canon[18];
    const bf16*  hw    = (const bf16*) canon[19];
    const float* hb    = (const float*)canon[20];

    // one-time weight pad (after conversion)
    pad_dtw<<<(LAYERS*DI*64 + 255)/256, blk, 0, stream>>>(dtw, dtw_pad);

    const int MG  = g*SEQ;
    const int nin2 = g*24;                // scan blocks per chunk (64 d each)

    // dispatch helper: fast path needs tile-clean dims AND >=192 blocks
    auto launch_gemm = [&](const bf16* A, int lda, const bf16* W, int ldw,
                           float* Cf, bf16* Cb, int ldc,
                           const float* bias, const float* chan_,
                           int M, int N, int K, int epi) {
        dim3 gr((M + 127)/128, (N + 127)/128);
        bool clean = (M & 127) == 0 && (N & 127) == 0 && (K & 31) == 0;
        if (clean && gr.x*gr.y >= 192)
            gemm_mfma_fast<<<gr, blk, 0, stream>>>(A, lda, W, ldw, Cf, Cb, ldc,
                                                   bias, chan_, N, K, epi);
        else
            gemm_mfma<<<gr, blk, 0, stream>>>(A, lda, W, ldw, Cf, Cb, ldc,
                                              bias, chan_, M, N, K, epi);
    };

    // ---- patch embed -> residual (fp32), MFMA epi3 ----
    for (int b0 = 0; b0 < BATCH; b0 += g) {
        gather_patches<<<MG, blk, 0, stream>>>(xin, Ap, b0);
        launch_gemm(Ap, 256, pw, 256,
                    residual + (size_t)b0*SEQ*DM, nullptr, DM,
                    pb, chan, MG, DM, 256, 3);
    }

    for (int l = 0; l < LAYERS; ++l) {
        ln768<<<M_TOK, blk, 0, stream>>>(residual, nw + l*DM, nb + l*DM, hn);
        for (int b0 = 0; b0 < BATCH; b0 += g) {
            const bf16* hng = hn + (size_t)b0*SEQ*DM;
            // fused in_proj: one GEMM, N=3072 (x | z) -> xz (grid 98x24, fast)
            launch_gemm(hng, DM, ipw + (size_t)l*2*DI*DM, DM,
                        nullptr, xz, XZW, nullptr, nullptr, MG, 2*DI, DM, 0);
            conv_silu<<<(MG*(DI/8))/256, blk, 0, stream>>>(xz, cw + (size_t)l*DI*4, cb + l*DI, xc);
            // x_proj: split-K=2 (grid 98x1x2, 24 K-iters per slice) -> fp32 partials
            {
                dim3 gr((MG + 127)/128, 1, 2);
                gemm_mfma<<<gr, blk, 0, stream>>>(xc, DI, xpw + (size_t)l*80*DI, DI,
                                                  dbcf, nullptr, 80, nullptr, nullptr,
                                                  MG, 80, DI/2, 5);
                dbc_combine<<<(MG*20 + 255)/256, blk, 0, stream>>>(dbcf, dbc, MG);
            }
            // dt_proj + softplus: padded K=64, grid 1176 -> fast path
            launch_gemm(dbc, DBCW, dtw_pad + (size_t)l*DI*64, 64,
                        nullptr, dtb, DI, dtbia + l*DI, nullptr, MG, DI, 64, 1);
            scan_pass1<<<(NCH-1)*nin2, blk, 0, stream>>>(dtb, xc, dbc,
                                                         Alog + (size_t)l*DI*DS,
                                                         hend, Pprod, nin2);
            scan_mid<<<nin2, blk, 0, stream>>>(hend, Pprod, hstart, nin2);
            // y written into dead x-half of xz (stride XZW)
            scan_pass2<<<NCH*nin2, blk, 0, stream>>>(dtb, xc, dbc,
                                                     Alog + (size_t)l*DI*DS,
                                                     Dpar + l*DI, hstart, xz, nin2);
            gate_ln<<<MG, dim3(192), 0, stream>>>(xz, snw + l*DI, snb + l*DI, gated);
            // out_proj += residual (MFMA epi2, grid 588 -> fast)
            launch_gemm(gated, DI, opw + (size_t)l*DM*DI, DI,
                        residual + (size_t)b0*SEQ*DM, nullptr, DM,
                        nullptr, nullptr, MG, DM, DI, 2);
        }
    }

    ln768<<<M_TOK, blk, 0, stream>>>(residual, nfw, nfb, hn);
    pool_partial<<<BATCH*NCH, blk, 0, stream>>>(hn, poolpart);
    pool_finish<<<(BATCH*DM)/256, blk, 0, stream>>>(poolpart, pooled);
    head_kernel<<<(BATCH*NCLS + 255)/256, blk, 0, stream>>>(flag, pooled, hw, hb, d_out);
}

// Round 15
// 3225.917 us; speedup vs baseline: 1.1723x; 1.1723x over previous
//
#include <hip/hip_runtime.h>
#include <hip/hip_bf16.h>

typedef __hip_bfloat16 bf16;
typedef __attribute__((ext_vector_type(8))) short short8;
typedef __attribute__((ext_vector_type(4))) float float4v;

#define BATCH 8
#define SEQ   1568            // 14*14*8 tokens per batch
#define M_TOK (BATCH*SEQ)     // 12544
#define DM    768
#define DI    1536
#define XZW   3072            // fused in_proj output row width (x | z)
#define DS    16
#define DTR   48
#define NCLS  1000
#define LAYERS 4
#define CHUNK 112             // scan chunk length (7 tiles of 16)
#define NCH   14              // SEQ / CHUNK
#define DBCW  128             // padded dbc row width

__device__ __forceinline__ float b2f(bf16 v){ return __bfloat162float(v); }
__device__ __forceinline__ bf16  f2b(float v){ return __float2bfloat16(v); }
__device__ __forceinline__ float us2f(unsigned short u){
    unsigned v = ((unsigned)u) << 16; float f; __builtin_memcpy(&f, &v, 4); return f;
}
__device__ __forceinline__ short f2bs(float v){
    bf16 r = f2b(v); unsigned short u; __builtin_memcpy(&u, &r, 2); return (short)u;
}
// async global->LDS, 16B per lane; LDS dest = uniform base + lane*16
__device__ __forceinline__ void gload_lds16(const void* g, void* l){
    __builtin_amdgcn_global_load_lds(
        (const __attribute__((address_space(1))) void*)g,
        (__attribute__((address_space(3))) void*)l, 16, 0, 0);
}
// VALU-pipe cross-lane add via DPP. CTRL immediate (template).
template<int CTRL>
__device__ __forceinline__ float dpp_add(float p){
    int pi; __builtin_memcpy(&pi, &p, 4);
    int mi = __builtin_amdgcn_update_dpp(pi, pi, CTRL, 0xF, 0xF, false);
    float m; __builtin_memcpy(&m, &mi, 4);
    return p + m;
}

// ---------------------------------------------------------------- dtype probe
__global__ void detect_dtype(const unsigned short* __restrict__ probe, unsigned* __restrict__ flag)
{
    if (threadIdx.x == 0 && blockIdx.x == 0) flag[0] = (probe[0] == 0) ? 1u : 0u;  // 1 = fp32
}

// ---------------------------------------------------------------- batched input conversion
struct CvtArgs {
    const void* src[21];
    void*       dst[21];
    int         n[21];       // element count
    int         n8[21];      // ceil(n/8)
    unsigned    f32mask;     // bit k: PERMUTED slot k converts to fp32
    int         total8;      // sum of n8
};

__global__ __launch_bounds__(256)
void convert_all8(CvtArgs a, const unsigned* __restrict__ flag)
{
    int g8 = blockIdx.x*256 + threadIdx.x;
    if (g8 >= a.total8) return;
    int i = 0, base = 0;
    while (g8 >= base + a.n8[i]) { base += a.n8[i]; ++i; }
    int j = (g8 - base)*8;
    bool in_f32  = flag[0] != 0;
    bool out_f32 = (a.f32mask >> i) & 1u;
    if (j + 8 <= a.n[i]) {
        if (in_f32) {
            float4v v0 = *(const float4v*)((const float*)a.src[i] + j);
            float4v v1 = *(const float4v*)((const float*)a.src[i] + j + 4);
            if (out_f32) {
                *(float4v*)((float*)a.dst[i] + j)     = v0;
                *(float4v*)((float*)a.dst[i] + j + 4) = v1;
            } else {
                short8 o;
                #pragma unroll
                for (int k = 0; k < 4; ++k) { o[k] = f2bs(v0[k]); o[k+4] = f2bs(v1[k]); }
                *(short8*)((short*)a.dst[i] + j) = o;
            }
        } else {
            short8 v = *(const short8*)((const short*)a.src[i] + j);
            if (out_f32) {
                float4v v0, v1;
                #pragma unroll
                for (int k = 0; k < 4; ++k) {
                    v0[k] = us2f((unsigned short)v[k]);
                    v1[k] = us2f((unsigned short)v[k+4]);
                }
                *(float4v*)((float*)a.dst[i] + j)     = v0;
                *(float4v*)((float*)a.dst[i] + j + 4) = v1;
            } else {
                *(short8*)((short*)a.dst[i] + j) = v;
            }
        }
    } else {
        for (int q = j; q < a.n[i]; ++q) {
            float v = in_f32 ? ((const float*)a.src[i])[q] : b2f(((const bf16*)a.src[i])[q]);
            if (out_f32) ((float*)a.dst[i])[q] = v;
            else         ((bf16*) a.dst[i])[q] = f2b(v);
        }
    }
}

// ---------------------------------------------------------------- weight pad (run once)
// dtw (L,DI,48) -> (L,DI,64) zero-padded cols
__global__ __launch_bounds__(256)
void pad_dtw(const bf16* __restrict__ src, bf16* __restrict__ dst)
{
    int idx = blockIdx.x*256 + threadIdx.x;          // < L*DI*64
    if (idx >= LAYERS*DI*64) return;
    int l = idx / (DI*64);
    int d = (idx / 64) % DI;
    int c = idx % 64;
    dst[idx] = (c < DTR) ? src[((size_t)l*DI + d)*DTR + c] : f2b(0.f);
}

// ---------------------------------------------------------------- gather patches (per batch-group)
__global__ __launch_bounds__(256)
void gather_patches(const bf16* __restrict__ x, bf16* __restrict__ Ap, int b0)
{
    size_t idx = (size_t)blockIdx.x*256 + threadIdx.x;
    int i = (int)(idx & 255);
    int m = (int)(idx >> 8);
    int b = b0 + m / SEQ, s = m % SEQ;
    int hw = s >> 3, c = s & 7;
    int h = hw / 14, w = hw % 14;
    int p = i >> 4, q = i & 15;
    Ap[idx] = x[(((size_t)(b*8 + c)*224) + h*16 + p)*224 + w*16 + q];
}

// ---------------------------------------------------------------- MFMA GEMM, ragged-safe (128x128, BK=32)
// Small grids (<192 blocks): VGPR-staged loads software-pipeline under MFMA.
// Split-K: gridDim.z slices; epi 5 stores fp32 partials per slice.
__global__ __launch_bounds__(256)
void gemm_mfma(const bf16* __restrict__ A, int lda,
               const bf16* __restrict__ W, int ldw,
               float* __restrict__ Cf, bf16* __restrict__ Cb, int ldc,
               const float* __restrict__ bias, const float* __restrict__ chan,
               int M, int N, int K, int epi)
{
    __shared__ short As[128*40];   // 32 + 8 pad elems per row (80B stride, 16B aligned)
    __shared__ short Bs[128*40];
    int kb = blockIdx.z * K;       // K-slice base (0 when gridDim.z==1)
    A += kb;  W += kb;
    int tid  = threadIdx.x;
    int m0   = blockIdx.x*128, n0 = blockIdx.y*128;
    int lane = tid & 63, wv = tid >> 6;
    int wm = (wv >> 1)*64, wn = (wv & 1)*64;
    int l15 = lane & 15, quad = lane >> 4;

    float4v acc[4][4];
    #pragma unroll
    for (int i = 0; i < 4; ++i)
        #pragma unroll
        for (int j = 0; j < 4; ++j) acc[i][j] = (float4v){0.f,0.f,0.f,0.f};

    const short8 zv8 = {0,0,0,0,0,0,0,0};
    for (int k0 = 0; k0 < K; k0 += 32) {
        #pragma unroll
        for (int u = 0; u < 2; ++u) {
            int c   = tid*2 + u;           // 512 chunks of 16B
            int row = c >> 2, ch = c & 3;
            bool kok = (k0 + ch*8 + 8) <= K;   // K is a multiple of 8
            short8 va = (kok && m0 + row < M)
                ? *(const short8*)((const short*)A + (size_t)(m0+row)*lda + k0 + ch*8) : zv8;
            *(short8*)(As + row*40 + ch*8) = va;
            short8 vb = (kok && n0 + row < N)
                ? *(const short8*)((const short*)W + (size_t)(n0+row)*ldw + k0 + ch*8) : zv8;
            *(short8*)(Bs + row*40 + ch*8) = vb;
        }
        __syncthreads();
        short8 av[4], bv[4];
        #pragma unroll
        for (int i = 0; i < 4; ++i) av[i] = *(const short8*)(As + (wm + i*16 + l15)*40 + quad*8);
        #pragma unroll
        for (int j = 0; j < 4; ++j) bv[j] = *(const short8*)(Bs + (wn + j*16 + l15)*40 + quad*8);
        #pragma unroll
        for (int i = 0; i < 4; ++i)
            #pragma unroll
            for (int j = 0; j < 4; ++j)
                acc[i][j] = __builtin_amdgcn_mfma_f32_16x16x32_bf16(av[i], bv[j], acc[i][j], 0, 0, 0);
        __syncthreads();
    }

    // C/D layout: col = lane&15, row = quad*4 + reg
    #pragma unroll
    for (int i = 0; i < 4; ++i) {
        #pragma unroll
        for (int j = 0; j < 4; ++j) {
            int gn = n0 + wn + j*16 + l15;
            if (gn >= N) continue;
            #pragma unroll
            for (int r = 0; r < 4; ++r) {
                int gm = m0 + wm + i*16 + quad*4 + r;
                if (gm >= M) continue;
                float v = acc[i][j][r];
                size_t off = (size_t)gm*ldc + gn;
                if (epi == 0)      Cb[off] = f2b(v);
                else if (epi == 1) {
                    v += bias[gn];
                    v = (v > 20.f) ? v : log1pf(__expf(v));
                    Cb[off] = f2b(v);
                }
                else if (epi == 2) Cf[off] += v;
                else if (epi == 5) Cf[(size_t)blockIdx.z*((size_t)M*ldc) + off] = v;
                else               Cf[off] = v + bias[gn] + chan[(size_t)(gm & 7)*N + gn];
            }
        }
    }
}

// ---------------------------------------------------------------- split-K combine for x_proj
__global__ __launch_bounds__(256)
void dbc_combine(const float* __restrict__ dbcf, bf16* __restrict__ dbc, int MG)
{
    int idx = blockIdx.x*256 + threadIdx.x;   // < MG*20
    if (idx >= MG*20) return;
    int m = idx / 20, c4 = (idx % 20)*4;
    float4v a = *(const float4v*)(dbcf + (size_t)m*80 + c4);
    float4v b = *(const float4v*)(dbcf + (size_t)MG*80 + (size_t)m*80 + c4);
    ushort4 o;
    o.x = (unsigned short)f2bs(a[0] + b[0]);
    o.y = (unsigned short)f2bs(a[1] + b[1]);
    o.z = (unsigned short)f2bs(a[2] + b[2]);
    o.w = (unsigned short)f2bs(a[3] + b[3]);
    *(ushort4*)((unsigned short*)dbc + (size_t)m*DBCW + c4) = o;
}

// ---------------------------------------------------------------- MFMA GEMM fast path (BK=32, linear LDS)
// Requires M%128==0, N%128==0, K%32==0, >=192 blocks (TLP hides barrier drain).
__global__ __launch_bounds__(256)
void gemm_mfma_fast(const bf16* __restrict__ A, int lda,
                    const bf16* __restrict__ W, int ldw,
                    float* __restrict__ Cf, bf16* __restrict__ Cb, int ldc,
                    const float* __restrict__ bias, const float* __restrict__ chan,
                    int N, int K, int epi)
{
    __shared__ short As[128*32];
    __shared__ short Bs[128*32];
    int tid  = threadIdx.x;
    int m0   = blockIdx.x*128, n0 = blockIdx.y*128;
    int lane = tid & 63, wv = tid >> 6;
    int wm = (wv >> 1)*64, wn = (wv & 1)*64;
    int l15 = lane & 15, quad = lane >> 4;

    int srow = (lane >> 2);          // row within 16-row chunk
    int skof = (lane & 3) * 8;       // k element offset within row

    float4v acc[4][4];
    #pragma unroll
    for (int i = 0; i < 4; ++i)
        #pragma unroll
        for (int j = 0; j < 4; ++j) acc[i][j] = (float4v){0.f,0.f,0.f,0.f};

    const short* Ab = (const short*)A;
    const short* Wb = (const short*)W;

    for (int k0 = 0; k0 < K; k0 += 32) {
        #pragma unroll
        for (int u = 0; u < 2; ++u) {
            int c = wv*2 + u;                 // chunk 0..7
            int row = c*16 + srow;
            gload_lds16(Ab + (size_t)(m0+row)*lda + k0 + skof, As + c*512);
            gload_lds16(Wb + (size_t)(n0+row)*ldw + k0 + skof, Bs + c*512);
        }
        __syncthreads();                       // drains vmcnt (compiler-inserted)
        short8 av[4], bv[4];
        #pragma unroll
        for (int i = 0; i < 4; ++i) av[i] = *(const short8*)(As + (wm + i*16 + l15)*32 + quad*8);
        #pragma unroll
        for (int j = 0; j < 4; ++j) bv[j] = *(const short8*)(Bs + (wn + j*16 + l15)*32 + quad*8);
        #pragma unroll
        for (int i = 0; i < 4; ++i)
            #pragma unroll
            for (int j = 0; j < 4; ++j)
                acc[i][j] = __builtin_amdgcn_mfma_f32_16x16x32_bf16(av[i], bv[j], acc[i][j], 0, 0, 0);
        __syncthreads();
    }

    #pragma unroll
    for (int i = 0; i < 4; ++i) {
        #pragma unroll
        for (int j = 0; j < 4; ++j) {
            int gn = n0 + wn + j*16 + l15;
            #pragma unroll
            for (int r = 0; r < 4; ++r) {
                int gm = m0 + wm + i*16 + quad*4 + r;
                float v = acc[i][j][r];
                size_t off = (size_t)gm*ldc + gn;
                if (epi == 0)      Cb[off] = f2b(v);
                else if (epi == 1) {
                    v += bias[gn];
                    v = (v > 20.f) ? v : log1pf(__expf(v));
                    Cb[off] = f2b(v);
                }
                else if (epi == 2) Cf[off] += v;
                else               Cf[off] = v + bias[gn] + chan[(size_t)(gm & 7)*N + gn];
            }
        }
    }
}

// ---------------------------------------------------------------- LayerNorm 768 (fp32 in, bf16 out)
// 192 threads x float4 (G13); 3-wave reduction
__global__ __launch_bounds__(192)
void ln768(const float* __restrict__ X, const float* __restrict__ w,
           const float* __restrict__ bb, bf16* __restrict__ out)
{
    __shared__ float red[6];
    size_t t = blockIdx.x;
    int tid = threadIdx.x;
    int i0 = tid*4;
    float4v v = *(const float4v*)(X + t*DM + i0);
    float s = v[0]+v[1]+v[2]+v[3];
    float s2 = v[0]*v[0]+v[1]*v[1]+v[2]*v[2]+v[3]*v[3];
    #pragma unroll
    for (int o = 32; o; o >>= 1) { s += __shfl_down(s, o, 64); s2 += __shfl_down(s2, o, 64); }
    if ((tid & 63) == 0) { red[tid >> 6] = s; red[(tid >> 6) + 3] = s2; }
    __syncthreads();
    s  = red[0]+red[1]+red[2];
    s2 = red[3]+red[4]+red[5];
    float mu  = s * (1.f/DM);
    float inv = rsqrtf(fmaxf(s2*(1.f/DM) - mu*mu, 0.f) + 1e-5f);
    float4v wq = *(const float4v*)(w + i0);
    float4v bq = *(const float4v*)(bb + i0);
    ushort4 o4;
    o4.x = (unsigned short)f2bs((v[0]-mu)*inv*wq[0] + bq[0]);
    o4.y = (unsigned short)f2bs((v[1]-mu)*inv*wq[1] + bq[1]);
    o4.z = (unsigned short)f2bs((v[2]-mu)*inv*wq[2] + bq[2]);
    o4.w = (unsigned short)f2bs((v[3]-mu)*inv*wq[3] + bq[3]);
    *(ushort4*)((unsigned short*)out + t*DM + i0) = o4;
}

// ---------------------------------------------------------------- causal depthwise conv (k=4) + silu
// reads x-half of fused xz (row stride XZW); writes dense DI-wide xc
__global__ __launch_bounds__(256)
void conv_silu(const bf16* __restrict__ xz, const float* __restrict__ cw,
               const float* __restrict__ cb, bf16* __restrict__ xc)
{
    size_t idx = (size_t)blockIdx.x*256 + threadIdx.x;   // < g*SEQ*DI/8
    int dv = (int)(idx % (DI/8));
    int m  = (int)(idx / (DI/8));
    int b = m / SEQ, t = m % SEQ;                        // local batch
    int d = dv*8;

    float4v cwq[8];
    #pragma unroll
    for (int j = 0; j < 8; ++j) cwq[j] = *(const float4v*)(cw + (size_t)(d+j)*4);

    float acc[8];
    #pragma unroll
    for (int j = 0; j < 8; ++j) acc[j] = cb[d+j];

    #pragma unroll
    for (int k = 0; k < 4; ++k) {
        int tt = t + k - 3;
        if (tt >= 0) {
            short8 v = *(const short8*)((const short*)xz + (size_t)(b*SEQ + tt)*XZW + d);
            #pragma unroll
            for (int j = 0; j < 8; ++j)
                acc[j] += us2f((unsigned short)v[j]) * cwq[j][k];
        }
    }
    short8 o;
    #pragma unroll
    for (int j = 0; j < 8; ++j) {
        float sig = 1.f/(1.f + __expf(-acc[j]));
        o[j] = f2bs(acc[j]*sig);
    }
    *(short8*)((short*)xc + idx*8) = o;
}

// ---------------------------------------------------------------- selective scan: chunked 2-pass,
// 4 states/lane (64 d x 4 state-quads per 256-thread block); DPP quad reduction.
// dbc rows DBCW-wide. pass2 writes y into the dead x-half of xz (row stride XZW).

__global__ __launch_bounds__(256)
void scan_pass1(const bf16* __restrict__ dt, const bf16* __restrict__ x,
                const bf16* __restrict__ dbc, const float* __restrict__ Alog,
                float* __restrict__ hend, float* __restrict__ Pprod, int nin2)
{
    __shared__ float dtT[2][64][20], xT[2][64][20];
    __shared__ float BsT[2][16][16];
    int c  = blockIdx.x / nin2;          // chunk 0..NCH-2
    int r  = blockIdx.x % nin2;
    int b  = r / 24;
    int d0 = (r % 24) * 64;
    int tid = threadIdx.x;
    int sq = tid & 3;        // state quad: states sq*4..sq*4+3
    int dl = tid >> 2;       // d-chain 0..63
    int d  = d0 + dl;

    float4v Aq = *(const float4v*)(Alog + (size_t)d*DS + sq*4);
    float A2[4], h[4];
    #pragma unroll
    for (int k = 0; k < 4; ++k) { A2[k] = -__expf(Aq[k]) * 1.44269504f; h[k] = 0.f; }
    float sdt = 0.f;

    int js = tid >> 4, dg = tid & 15;        // dt/x staging: step js, d-group dg*4
    bool doB = tid < 64;
    int j2 = tid >> 2;                       // B staging step (tid<64)

    const unsigned short* pdt = (const unsigned short*)dt + ((size_t)b*SEQ + js)*DI + d0 + dg*4;
    const unsigned short* px  = (const unsigned short*)x  + ((size_t)b*SEQ + js)*DI + d0 + dg*4;
    const unsigned short* pbc = (const unsigned short*)dbc + ((size_t)b*SEQ + (j2 & 15))*DBCW + DTR + sq*4;
    int tbase = c * CHUNK;
    const int NT = CHUNK/16;

    ushort4 vdt, vx, vbc;
    auto stage = [&](int buf){
        dtT[buf][dg*4+0][js] = us2f(vdt.x); dtT[buf][dg*4+1][js] = us2f(vdt.y);
        dtT[buf][dg*4+2][js] = us2f(vdt.z); dtT[buf][dg*4+3][js] = us2f(vdt.w);
        xT [buf][dg*4+0][js] = us2f(vx.x);  xT [buf][dg*4+1][js] = us2f(vx.y);
        xT [buf][dg*4+2][js] = us2f(vx.z);  xT [buf][dg*4+3][js] = us2f(vx.w);
        if (doB)
            *(float4v*)&BsT[buf][j2][sq*4] =
                (float4v){us2f(vbc.x), us2f(vbc.y), us2f(vbc.z), us2f(vbc.w)};
    };
    auto fetch = [&](int T){
        vdt = *(const ushort4*)(pdt + (size_t)(tbase + T*16)*DI);
        vx  = *(const ushort4*)(px  + (size_t)(tbase + T*16)*DI);
        if (doB) vbc = *(const ushort4*)(pbc + (size_t)(tbase + T*16)*DBCW);
    };

    fetch(0); stage(0); fetch(1);
    __syncthreads();

    for (int t = 0; t < NT; ++t) {
        int cur = t & 1;
        if (t+1 < NT) stage(cur^1);
        if (t+2 < NT) fetch(t+2);
        #pragma unroll
        for (int jj = 0; jj < 16; jj += 4) {
            float4v dtq = *(const float4v*)&dtT[cur][dl][jj];
            float4v xq  = *(const float4v*)&xT [cur][dl][jj];
            #pragma unroll
            for (int k2 = 0; k2 < 4; ++k2) {
                float dtv = dtq[k2];
                float dtx = dtv * xq[k2];
                float4v Bq = *(const float4v*)&BsT[cur][jj+k2][sq*4];
                #pragma unroll
                for (int k = 0; k < 4; ++k)
                    h[k] = exp2f(dtv*A2[k])*h[k] + dtx*Bq[k];
                sdt += dtv;
            }
        }
        __syncthreads();
    }
    size_t o = (((size_t)c*nin2 + r)*256 + tid)*4;
    *(float4v*)(hend + o) = (float4v){h[0], h[1], h[2], h[3]};
    *(float4v*)(Pprod + o) = (float4v){exp2f(A2[0]*sdt), exp2f(A2[1]*sdt),
                                       exp2f(A2[2]*sdt), exp2f(A2[3]*sdt)};
}

__global__ __launch_bounds__(256)
void scan_mid(const float* __restrict__ hend, const float* __restrict__ Pprod,
              float* __restrict__ hstart, int nin2)
{
    int r = blockIdx.x, tid = threadIdx.x;
    float4v h = (float4v){0.f,0.f,0.f,0.f};
    *(float4v*)(hstart + ((size_t)r*256 + tid)*4) = h;
    for (int c = 1; c < NCH; ++c) {
        size_t p = (((size_t)(c-1)*nin2 + r)*256 + tid)*4;
        float4v P  = *(const float4v*)(Pprod + p);
        float4v he = *(const float4v*)(hend + p);
        h = P*h + he;
        *(float4v*)(hstart + (((size_t)c*nin2 + r)*256 + tid)*4) = h;
    }
}

__global__ __launch_bounds__(256)
void scan_pass2(const bf16* __restrict__ dt, const bf16* __restrict__ x,
                const bf16* __restrict__ dbc, const float* __restrict__ Alog,
                const float* __restrict__ Dpar, const float* __restrict__ hstart,
                bf16* __restrict__ y, int nin2)   // y: row stride XZW (xz x-half)
{
    __shared__ float dtT[2][64][20], xT[2][64][20];
    __shared__ float BsT[2][16][16], CsT[2][16][16];
    __shared__ bf16  ys[16][64];
    int c  = blockIdx.x / nin2;
    int r  = blockIdx.x % nin2;
    int b  = r / 24;
    int d0 = (r % 24) * 64;
    int tid = threadIdx.x;
    int sq = tid & 3;
    int dl = tid >> 2;
    int d  = d0 + dl;

    float4v Aq = *(const float4v*)(Alog + (size_t)d*DS + sq*4);
    float A2[4], h[4];
    {
        float4v h0 = *(const float4v*)(hstart + (((size_t)c*nin2 + r)*256 + tid)*4);
        #pragma unroll
        for (int k = 0; k < 4; ++k) { A2[k] = -__expf(Aq[k]) * 1.44269504f; h[k] = h0[k]; }
    }
    float Dv = Dpar[d];

    int js = tid >> 4, dg = tid & 15;
    bool doBC = tid < 128;
    int j2 = (tid & 63) >> 2;

    const unsigned short* pdt = (const unsigned short*)dt + ((size_t)b*SEQ + js)*DI + d0 + dg*4;
    const unsigned short* px  = (const unsigned short*)x  + ((size_t)b*SEQ + js)*DI + d0 + dg*4;
    const unsigned short* pbc = (const unsigned short*)dbc + ((size_t)b*SEQ + j2)*DBCW + DTR
                                + ((tid >= 64) ? DS : 0) + sq*4;
    float* bc0 = (tid < 64) ? &BsT[0][j2][sq*4] : &CsT[0][j2][sq*4];
    int tbase = c * CHUNK;
    const int NT = CHUNK/16;

    ushort4 vdt, vx, vbc;
    auto stage = [&](int buf){
        dtT[buf][dg*4+0][js] = us2f(vdt.x); dtT[buf][dg*4+1][js] = us2f(vdt.y);
        dtT[buf][dg*4+2][js] = us2f(vdt.z); dtT[buf][dg*4+3][js] = us2f(vdt.w);
        xT [buf][dg*4+0][js] = us2f(vx.x);  xT [buf][dg*4+1][js] = us2f(vx.y);
        xT [buf][dg*4+2][js] = us2f(vx.z);  xT [buf][dg*4+3][js] = us2f(vx.w);
        if (doBC)
            *(float4v*)(bc0 + (size_t)buf*256) =
                (float4v){us2f(vbc.x), us2f(vbc.y), us2f(vbc.z), us2f(vbc.w)};
    };
    auto fetch = [&](int T){
        vdt = *(const ushort4*)(pdt + (size_t)(tbase + T*16)*DI);
        vx  = *(const ushort4*)(px  + (size_t)(tbase + T*16)*DI);
        if (doBC) vbc = *(const ushort4*)(pbc + (size_t)(tbase + T*16)*DBCW);
    };

    fetch(0); stage(0); fetch(1);
    __syncthreads();

    for (int t = 0; t < NT; ++t) {
        int cur = t & 1;
        if (t+1 < NT) stage(cur^1);
        if (t+2 < NT) fetch(t+2);

        #pragma unroll
        for (int jj = 0; jj < 16; jj += 4) {
            float4v dtq = *(const float4v*)&dtT[cur][dl][jj];
            float4v xq  = *(const float4v*)&xT [cur][dl][jj];
            #pragma unroll
            for (int k2 = 0; k2 < 4; ++k2) {
                float dtv = dtq[k2];
                float xv  = xq[k2];
                float dtx = dtv * xv;
                float4v Bq = *(const float4v*)&BsT[cur][jj+k2][sq*4];
                float4v Cq = *(const float4v*)&CsT[cur][jj+k2][sq*4];
                float p = 0.f;
                #pragma unroll
                for (int k = 0; k < 4; ++k) {
                    h[k] = exp2f(dtv*A2[k])*h[k] + dtx*Bq[k];
                    p += h[k]*Cq[k];
                }
                p = dpp_add<0xB1>(p);    // quad_perm xor1 (within one d's quad)
                p = dpp_add<0x4E>(p);    // quad_perm xor2
                if (sq == 0) ys[jj+k2][dl] = f2b(p + Dv*xv);
            }
        }
        __syncthreads();                 // ys ready + next buf staged
        {
            size_t rowm = (size_t)(b*SEQ + tbase + t*16 + js);
            ushort4 vy = *(const ushort4*)((const unsigned short*)&ys[js][0] + dg*4);
            *(ushort4*)((unsigned short*)y + rowm*XZW + d0 + dg*4) = vy;
        }
        __syncthreads();                 // ys consumed
    }
}

// ---------------------------------------------------------------- LN(1536)*silu(z) gate
// y and z are the two halves of fused xz (row stride XZW); out dense DI-wide.
__global__ __launch_bounds__(192)
void gate_ln(const bf16* __restrict__ xz,
             const float* __restrict__ w, const float* __restrict__ bb,
             bf16* __restrict__ out)
{
    __shared__ float red[6];
    size_t t = blockIdx.x;
    int tid = threadIdx.x;
    int i0 = tid*8;
    short8 y8 = *(const short8*)((const short*)xz + t*XZW + i0);
    short8 z8 = *(const short8*)((const short*)xz + t*XZW + DI + i0);
    float vy[8];
    float s = 0.f, s2 = 0.f;
    #pragma unroll
    for (int j = 0; j < 8; ++j) {
        vy[j] = us2f((unsigned short)y8[j]);
        s += vy[j]; s2 += vy[j]*vy[j];
    }
    #pragma unroll
    for (int o = 32; o; o >>= 1) { s += __shfl_down(s, o, 64); s2 += __shfl_down(s2, o, 64); }
    if ((tid & 63) == 0) { red[tid >> 6] = s; red[(tid >> 6) + 3] = s2; }
    __syncthreads();
    s  = red[0]+red[1]+red[2];
    s2 = red[3]+red[4]+red[5];
    float mu  = s * (1.f/DI);
    float inv = rsqrtf(fmaxf(s2*(1.f/DI) - mu*mu, 0.f) + 1e-5f);
    float4v w0 = *(const float4v*)(w + i0);
    float4v w1 = *(const float4v*)(w + i0 + 4);
    float4v b0 = *(const float4v*)(bb + i0);
    float4v b1 = *(const float4v*)(bb + i0 + 4);
    short8 o8;
    #pragma unroll
    for (int j = 0; j < 8; ++j) {
        float zv = us2f((unsigned short)z8[j]);
        float sig = 1.f/(1.f + __expf(-zv));
        float wj = (j < 4) ? w0[j] : w1[j-4];
        float bj = (j < 4) ? b0[j] : b1[j-4];
        o8[j] = f2bs(((vy[j]-mu)*inv*wj + bj) * (zv*sig));
    }
    *(short8*)((short*)out + t*DI + i0) = o8;
}

// ---------------------------------------------------------------- mean pool, 2-stage
__global__ __launch_bounds__(256)
void pool_partial(const bf16* __restrict__ hf, float* __restrict__ part)
{
    int blk = blockIdx.x;            // BATCH*14
    int b = blk / NCH, c = blk % NCH;
    int tid = threadIdx.x;
    const bf16* p = hf + ((size_t)b*SEQ + c*CHUNK)*DM;
    float s0 = 0.f, s1 = 0.f, s2 = 0.f;
    for (int t = 0; t < CHUNK; ++t) {
        s0 += b2f(p[(size_t)t*DM + tid]);
        s1 += b2f(p[(size_t)t*DM + tid + 256]);
        s2 += b2f(p[(size_t)t*DM + tid + 512]);
    }
    part[(size_t)blk*DM + tid]       = s0;
    part[(size_t)blk*DM + tid + 256] = s1;
    part[(size_t)blk*DM + tid + 512] = s2;
}

__global__ __launch_bounds__(256)
void pool_finish(const float* __restrict__ part, float* __restrict__ pooled)
{
    int idx = blockIdx.x*256 + threadIdx.x;   // < BATCH*DM
    int b = idx / DM, dm = idx % DM;
    float s = 0.f;
    for (int c = 0; c < NCH; ++c) s += part[((size_t)b*NCH + c)*DM + dm];
    pooled[idx] = s * (1.f/SEQ);
}

// ---------------------------------------------------------------- classifier head
__global__ __launch_bounds__(256)
void head_kernel(const unsigned* __restrict__ flag,
                 const float* __restrict__ pooled, const bf16* __restrict__ hw,
                 const float* __restrict__ hb, void* __restrict__ out)
{
    int idx = blockIdx.x*256 + threadIdx.x;
    if (idx >= BATCH*NCLS) return;
    int b = idx & 7, n = idx >> 3;
    const float* p = pooled + b*DM;
    const unsigned short* w = (const unsigned short*)hw + (size_t)n*DM;
    float acc = hb[n];
    for (int k = 0; k < DM; k += 4) {
        ushort4 wv = *(const ushort4*)(w + k);
        acc += p[k]*us2f(wv.x) + p[k+1]*us2f(wv.y) + p[k+2]*us2f(wv.z) + p[k+3]*us2f(wv.w);
    }
    int o = b*NCLS + n;
    if (flag[0]) ((float*)out)[o] = acc;
    else         ((bf16*)out)[o]  = f2b(acc);
}

// ================================================================ launcher
extern "C" void kernel_launch(void* const* d_in, const int* in_sizes, int n_in,
                              void* d_out, int out_size, void* d_ws, size_t ws_size,
                              hipStream_t stream)
{
    (void)n_in; (void)out_size;
    dim3 blk(256);

    const bool is_f32[21] = { false, false, true, true, true, true, false, true, true,
                              false, false, true,  true, true, true, true, false,
                              true,  true,  false, true };

    size_t off = 0;
    auto carve = [&](size_t bytes) -> void* {
        void* q = (char*)d_ws + off;
        off += (bytes + 255) & ~(size_t)255;
        return q;
    };

    unsigned* flag = (unsigned*)carve(256);
    void* canon[21];
    for (int i = 0; i < 21; ++i)
        canon[i] = carve((size_t)in_sizes[i] * (is_f32[i] ? 4 : 2));

    float* residual = (float*)carve((size_t)M_TOK*DM*4);
    bf16*  hn       = (bf16*) carve((size_t)M_TOK*DM*2);
    float* pooled   = (float*)carve((size_t)BATCH*DM*4);
    float* poolpart = (float*)carve((size_t)BATCH*NCH*DM*4);
    bf16*  dtw_pad  = (bf16*) carve((size_t)LAYERS*DI*64*2);

    const size_t scanbuf1 = (size_t)NCH*96*256*4;   // per g-unit, per array
    const size_t inner1 = (((size_t)SEQ*XZW*2 + 255) & ~(size_t)255)      // xz
                          + 2*(((size_t)SEQ*DI*2 + 255) & ~(size_t)255)   // xc, dtb
                          + (((size_t)SEQ*DBCW*2 + 255) & ~(size_t)255)   // dbc
                          + 2*(((size_t)SEQ*80*4 + 255) & ~(size_t)255)   // dbcf (2 K-slices)
                          + 3*((scanbuf1 + 255) & ~(size_t)255);
    int g = 8;
    while (g > 1 && off + (size_t)g*inner1 > ws_size) g >>= 1;

    bf16* xz  = (bf16*)carve((size_t)g*SEQ*XZW*2);  // fused in_proj out; x-half doubles as Ap / ybuf
    bf16* xc  = (bf16*)carve((size_t)g*SEQ*DI*2);
    bf16* dtb = (bf16*)carve((size_t)g*SEQ*DI*2);   // also gated
    bf16* dbc = (bf16*)carve((size_t)g*SEQ*DBCW*2);
    float* dbcf = (float*)carve((size_t)g*SEQ*80*4*2);   // split-K partials
    float* hend   = (float*)carve((size_t)g*scanbuf1);
    float* Pprod  = (float*)carve((size_t)g*scanbuf1);
    float* hstart = (float*)carve((size_t)g*scanbuf1);
    bf16* Ap    = xz;          // patch staging (pre-layer, whole buffer free)
    bf16* gated = dtb;

    detect_dtype<<<1, 64, 0, stream>>>((const unsigned short*)d_in[4], flag);

    // ---- single batched conversion, 8 elems/thread; size-desc order ----
    {
        int order[21];
        for (int i = 0; i < 21; ++i) order[i] = i;
        for (int a = 0; a < 21; ++a)
            for (int b2 = a+1; b2 < 21; ++b2)
                if (in_sizes[order[b2]] > in_sizes[order[a]]) {
                    int tmp = order[a]; order[a] = order[b2]; order[b2] = tmp;
                }
        CvtArgs ca;
        ca.f32mask = 0; ca.total8 = 0;
        for (int k = 0; k < 21; ++k) {
            int i = order[k];
            ca.src[k] = d_in[i];
            ca.dst[k] = canon[i];
            ca.n[k]   = in_sizes[i];
            ca.n8[k]  = (in_sizes[i] + 7)/8;
            ca.total8 += ca.n8[k];
            if (is_f32[i]) ca.f32mask |= (1u << k);
        }
        convert_all8<<<(ca.total8 + 255)/256, blk, 0, stream>>>(ca, flag);
    }

    const bf16*  xin   = (const bf16*) canon[0];
    const bf16*  pw    = (const bf16*) canon[1];
    const float* pb    = (const float*)canon[2];
    const float* chan  = (const float*)canon[3];
    const float* nw    = (const float*)canon[4];
    const float* nb    = (const float*)canon[5];
    const bf16*  ipw   = (const bf16*) canon[6];
    const float* cw    = (const float*)canon[7];
    const float* cb    = (const float*)canon[8];
    const bf16*  xpw   = (const bf16*) canon[9];
    const bf16*  dtw   = (const bf16*) canon[10];
    const float* dtbia = (const float*)canon[11];
    const float* Alog  = (const float*)canon[12];
    const float* Dpar  = (const float*)canon[13];
    const float* snw   = (const float*)canon[14];
    const float* snb   = (const float*)canon[15];
    const bf16*  opw   = (const bf16*) canon[16];
    const float* nfw   = (const float*)canon[17];
    const float* nfb   = (const float*)canon[18];
    const bf16*  hw    = (const bf16*) canon[19];
    const float* hb    = (const float*)canon[20];

    // one-time weight pad (after conversion)
    pad_dtw<<<(LAYERS*DI*64 + 255)/256, blk, 0, stream>>>(dtw, dtw_pad);

    const int MG  = g*SEQ;
    const int nin2 = g*24;                // scan blocks per chunk (64 d each)

    // dispatch helper: fast path needs tile-clean dims AND >=192 blocks
    auto launch_gemm = [&](const bf16* A, int lda, const bf16* W, int ldw,
                           float* Cf, bf16* Cb, int ldc,
                           const float* bias, const float* chan_,
                           int M, int N, int K, int epi) {
        dim3 gr((M + 127)/128, (N + 127)/128);
        bool clean = (M & 127) == 0 && (N & 127) == 0 && (K & 31) == 0;
        if (clean && gr.x*gr.y >= 192)
            gemm_mfma_fast<<<gr, blk, 0, stream>>>(A, lda, W, ldw, Cf, Cb, ldc,
                                                   bias, chan_, N, K, epi);
        else
            gemm_mfma<<<gr, blk, 0, stream>>>(A, lda, W, ldw, Cf, Cb, ldc,
                                              bias, chan_, M, N, K, epi);
    };

    // ---- patch embed -> residual (fp32), MFMA epi3 ----
    for (int b0 = 0; b0 < BATCH; b0 += g) {
        gather_patches<<<MG, blk, 0, stream>>>(xin, Ap, b0);
        launch_gemm(Ap, 256, pw, 256,
                    residual + (size_t)b0*SEQ*DM, nullptr, DM,
                    pb, chan, MG, DM, 256, 3);
    }

    for (int l = 0; l < LAYERS; ++l) {
        ln768<<<M_TOK, dim3(192), 0, stream>>>(residual, nw + l*DM, nb + l*DM, hn);
        for (int b0 = 0; b0 < BATCH; b0 += g) {
            const bf16* hng = hn + (size_t)b0*SEQ*DM;
            // fused in_proj: one GEMM, N=3072 (x | z) -> xz (grid 98x24, fast)
            launch_gemm(hng, DM, ipw + (size_t)l*2*DI*DM, DM,
                        nullptr, xz, XZW, nullptr, nullptr, MG, 2*DI, DM, 0);
            conv_silu<<<(MG*(DI/8))/256, blk, 0, stream>>>(xz, cw + (size_t)l*DI*4, cb + l*DI, xc);
            // x_proj: split-K=2 (grid 98x1x2, 24 K-iters per slice) -> fp32 partials
            {
                dim3 gr((MG + 127)/128, 1, 2);
                gemm_mfma<<<gr, blk, 0, stream>>>(xc, DI, xpw + (size_t)l*80*DI, DI,
                                                  dbcf, nullptr, 80, nullptr, nullptr,
                                                  MG, 80, DI/2, 5);
                dbc_combine<<<(MG*20 + 255)/256, blk, 0, stream>>>(dbcf, dbc, MG);
            }
            // dt_proj + softplus: padded K=64, grid 1176 -> fast path
            launch_gemm(dbc, DBCW, dtw_pad + (size_t)l*DI*64, 64,
                        nullptr, dtb, DI, dtbia + l*DI, nullptr, MG, DI, 64, 1);
            scan_pass1<<<(NCH-1)*nin2, blk, 0, stream>>>(dtb, xc, dbc,
                                                         Alog + (size_t)l*DI*DS,
                                                         hend, Pprod, nin2);
            scan_mid<<<nin2, blk, 0, stream>>>(hend, Pprod, hstart, nin2);
            // y written into dead x-half of xz (stride XZW)
            scan_pass2<<<NCH*nin2, blk, 0, stream>>>(dtb, xc, dbc,
                                                     Alog + (size_t)l*DI*DS,
                                                     Dpar + l*DI, hstart, xz, nin2);
            gate_ln<<<MG, dim3(192), 0, stream>>>(xz, snw + l*DI, snb + l*DI, gated);
            // out_proj += residual (MFMA epi2, grid 588 -> fast)
            launch_gemm(gated, DI, opw + (size_t)l*DM*DI, DI,
                        residual + (size_t)b0*SEQ*DM, nullptr, DM,
                        nullptr, nullptr, MG, DM, DI, 2);
        }
    }

    ln768<<<M_TOK, dim3(192), 0, stream>>>(residual, nfw, nfb, hn);
    pool_partial<<<BATCH*NCH, blk, 0, stream>>>(hn, poolpart);
    pool_finish<<<(BATCH*DM)/256, blk, 0, stream>>>(poolpart, pooled);
    head_kernel<<<(BATCH*NCLS + 255)/256, blk, 0, stream>>>(flag, pooled, hw, hb, d_out);
}